// Round 7
// baseline (558.433 us; speedup 1.0000x reference)
//
#include <hip/hip_runtime.h>

#define B_ 4
#define N_ 16384
#define HID_ 512
#define H_ 8
#define M_ 32
#define D_ 64

typedef __attribute__((ext_vector_type(8))) short short8;
typedef __attribute__((ext_vector_type(4))) float f32x4;

__device__ __forceinline__ short f2bf(float f) {
    unsigned u = __float_as_uint(f);
    u += 0x7fffu + ((u >> 16) & 1u);
    return (short)(u >> 16);
}
__device__ __forceinline__ float bf2f(short s) {
    return __uint_as_float(((unsigned)(unsigned short)s) << 16);
}
__device__ __forceinline__ unsigned pack2(float a, float b) {
    return (unsigned)(unsigned short)f2bf(a) | ((unsigned)(unsigned short)f2bf(b) << 16);
}
__device__ __forceinline__ void gl_lds16(const short* g, short* l) {
    __builtin_amdgcn_global_load_lds((const __attribute__((address_space(1))) unsigned*)g,
                                     (__attribute__((address_space(3))) unsigned*)l, 16, 0, 0);
}

// --------------------------------------------- x (f32) -> bf16, streaming convert
__global__ void k_cvt(const float* __restrict__ src, short* __restrict__ dst) {
    int i = blockIdx.x * 256 + threadIdx.x;   // 8 elements per thread
    const f32x4* s = (const f32x4*)(src) + (size_t)i * 2;
    f32x4 a = s[0], b = s[1];
    short8 o;
    o[0] = f2bf(a[0]); o[1] = f2bf(a[1]); o[2] = f2bf(a[2]); o[3] = f2bf(a[3]);
    o[4] = f2bf(b[0]); o[5] = f2bf(b[1]); o[6] = f2bf(b[2]); o[7] = f2bf(b[3]);
    ((short8*)dst)[i] = o;
}

// ---------------- prep: blocks 0-255 = Weff fold (+ misc outputs in block 0);
//                  blocks 256-319 = wkv_w v-half transpose (64x64 LDS tiles).
// Weff = Wk.wtq^T: scores = (x@Wk+bk).wtq^T = x@Weff + beff (exact algebra,
// f32 accumulate, single bf16 rounding).
__global__ __launch_bounds__(256)
void k_prep(const float* __restrict__ alpha, float* __restrict__ a_out,
            float* __restrict__ z_out, const float* __restrict__ wkv_w,
            const float* __restrict__ wkv_b, const float* __restrict__ wtq,
            short* __restrict__ WeffT, float* __restrict__ beff,
            short* __restrict__ wt) {
    const int bid = blockIdx.x, t = threadIdx.x;
    if (bid < 256) {
        __shared__ float wq_s[64];
        const int c = bid;          // h*32+m
        const int h = c >> 5;
        if (t < 64) wq_s[t] = wtq[c * 64 + t];
        __syncthreads();
#pragma unroll
        for (int kk = 0; kk < 2; ++kk) {
            const int k = kk * 256 + t;
            const float* wr = wkv_w + (size_t)k * 1024 + h * 64;
            float a = 0.f;
#pragma unroll
            for (int d = 0; d < 64; ++d) a += wr[d] * wq_s[d];
            WeffT[c * 512 + k] = f2bf(a);    // coalesced across t
        }
        if (t == 0) {
            float a = 0.f;
            for (int d = 0; d < 64; ++d) a += wkv_b[h * 64 + d] * wq_s[d];
            beff[c] = a;
        }
        if (bid == 0) {
            if (t < H_) a_out[t] = alpha[t];
            z_out[t] = 0.f;  // 256 = H_*M_
        }
    } else {
        __shared__ float ls[64][65];
        const int b2 = bid - 256;
        const int n0 = ((b2 & 7) + 8) * 64, k0 = (b2 >> 3) * 64;
#pragma unroll
        for (int p = 0; p < 16; ++p) {
            int idx = p * 256 + t;
            int kk = idx >> 6, nn = idx & 63;
            ls[kk][nn] = wkv_w[(size_t)(k0 + kk) * 1024 + n0 + nn];
        }
        __syncthreads();
#pragma unroll
        for (int p = 0; p < 16; ++p) {
            int idx = p * 256 + t;
            int nn = idx >> 6, kk = idx & 63;
            wt[(size_t)(n0 + nn) * 512 + k0 + kk] = f2bf(ls[kk][nn]);
        }
    }
}

// ------------------------------------- MFMA GEMM (m97 + XCD swz + BK=64 + T2 swz)
// Used only for: out = swT @ Pt^T + out_b (grid (4,512)).
template <bool OUT_BF16>
__global__ __launch_bounds__(256, 2)
void mfma_gemm(const short* __restrict__ A, const short* __restrict__ Bt,
               const float* __restrict__ bias, void* __restrict__ Cv,
               int K, int Ncols, int b_stride, int rows_per_b, int lgx) {
    __shared__ short As[128 * 64];
    __shared__ short Bs[128 * 64];
    const int t = threadIdx.x;
    const int nwg = gridDim.x * gridDim.y;
    int id = blockIdx.y * gridDim.x + blockIdx.x;
    id = (id & 7) * (nwg >> 3) + (id >> 3);
    const int col0 = (id & ((1 << lgx) - 1)) * 128;
    const int row0 = (id >> lgx) * 128;
    const short* Bblk = Bt;
    if (b_stride) Bblk += (size_t)(row0 / rows_per_b) * (size_t)b_stride;

    int srow[4], scol[4];
#pragma unroll
    for (int c = 0; c < 4; ++c) {
        int lin = (c * 256 + t) * 16;
        int logo = lin ^ (((lin >> 7) & 7) << 4);
        srow[c] = logo >> 7;
        scol[c] = (logo & 127) >> 1;   // shorts
    }

    const int w = t >> 6;
    const int L = t & 63;
    const int wm = (w >> 1) << 6;
    const int wn = (w & 1) << 6;
    const int lm = L & 15;
    const int lq = L >> 4;

    f32x4 acc[4][4];
#pragma unroll
    for (int i = 0; i < 4; ++i)
#pragma unroll
        for (int j = 0; j < 4; ++j) acc[i][j] = (f32x4){0.f, 0.f, 0.f, 0.f};

    for (int k0 = 0; k0 < K; k0 += 64) {
#pragma unroll
        for (int c = 0; c < 4; ++c) {
            gl_lds16(A + (size_t)(row0 + srow[c]) * K + k0 + scol[c], &As[(c * 256 + t) * 8]);
            gl_lds16(Bblk + (size_t)(col0 + srow[c]) * K + k0 + scol[c], &Bs[(c * 256 + t) * 8]);
        }
        __syncthreads();
#pragma unroll
        for (int ks = 0; ks < 2; ++ks) {
            short8 af[4], bfr[4];
#pragma unroll
            for (int i = 0; i < 4; ++i) {
                const int row = wm + (i << 4) + lm;
                int pb = (row << 7) + (ks << 6) + (lq << 4);
                pb ^= (row & 7) << 4;
                af[i] = *(const short8*)&As[pb >> 1];
            }
#pragma unroll
            for (int j = 0; j < 4; ++j) {
                const int row = wn + (j << 4) + lm;
                int pb = (row << 7) + (ks << 6) + (lq << 4);
                pb ^= (row & 7) << 4;
                bfr[j] = *(const short8*)&Bs[pb >> 1];
            }
#pragma unroll
            for (int i = 0; i < 4; ++i)
#pragma unroll
                for (int j = 0; j < 4; ++j)
                    acc[i][j] = __builtin_amdgcn_mfma_f32_16x16x32_bf16(af[i], bfr[j], acc[i][j], 0, 0, 0);
        }
        __syncthreads();
    }
#pragma unroll
    for (int i = 0; i < 4; ++i) {
#pragma unroll
        for (int j = 0; j < 4; ++j) {
            const int gr = row0 + wm + (i << 4) + (lq << 2);
            const int gc = col0 + wn + (j << 4) + lm;
            const float bv = bias[gc];
#pragma unroll
            for (int r = 0; r < 4; ++r) {
                float v = acc[i][j][r] + bv;
                if constexpr (OUT_BF16)
                    ((short*)Cv)[(size_t)(gr + r) * Ncols + gc] = f2bf(v);
                else
                    ((float*)Cv)[(size_t)(gr + r) * Ncols + gc] = v;
            }
        }
    }
}

// ------------------- merged v-GEMM + score-GEMM: one dispatch, 512 row-panels x
// 6 col-groups. cg 0-3: v = x@Wv + bv (bf16 store). cg 4-5: S = x@Weff + beff
// -> softmax epilogue (R6 k_scoreg verbatim). Merging makes the 6 col-tiles of a
// row panel XCD-adjacent -> x_bf panel fetched from HBM once (was twice).
__global__ __launch_bounds__(256, 2)
void k_vs(const short* __restrict__ A, const short* __restrict__ wkvTv,
          const float* __restrict__ wkv_b, const short* __restrict__ WeffT,
          const float* __restrict__ beff, const float* __restrict__ alpha,
          short* __restrict__ vout, float* __restrict__ sw_out,
          short* __restrict__ swT, float* __restrict__ pws) {
    __shared__ __attribute__((aligned(16))) short smem[16384];  // 32 KB
    short* As = smem;              // 128x64 (main loop)
    short* Bs = smem + 8192;       // 128x64 (main loop)
    short* wT_s = smem;            // [128 col][128 tok], reused after loop (score)
    const int t = threadIdx.x;
    int id = blockIdx.x;
    id = (id & 7) * 384 + (id >> 3);          // XCD swizzle, nwg=3072
    const int cg = id % 6;                    // 0-3 v, 4-5 score
    const int row0 = (id / 6) * 128;
    const int K = 512;
    const short* Bbase = (cg < 4) ? (wkvTv + (size_t)(cg * 128) * 512)
                                  : (WeffT + (size_t)((cg - 4) * 128) * 512);

    int srow[4], scol[4];
#pragma unroll
    for (int c = 0; c < 4; ++c) {
        int lin = (c * 256 + t) * 16;
        int logo = lin ^ (((lin >> 7) & 7) << 4);
        srow[c] = logo >> 7;
        scol[c] = (logo & 127) >> 1;
    }
    const int w = t >> 6;
    const int L = t & 63;
    const int wm = (w >> 1) << 6;
    const int wn = (w & 1) << 6;
    const int lm = L & 15;
    const int lq = L >> 4;

    f32x4 acc[4][4];
#pragma unroll
    for (int i = 0; i < 4; ++i)
#pragma unroll
        for (int j = 0; j < 4; ++j) acc[i][j] = (f32x4){0.f, 0.f, 0.f, 0.f};

    for (int k0 = 0; k0 < K; k0 += 64) {
#pragma unroll
        for (int c = 0; c < 4; ++c) {
            gl_lds16(A + (size_t)(row0 + srow[c]) * K + k0 + scol[c], &As[(c * 256 + t) * 8]);
            gl_lds16(Bbase + (size_t)(srow[c]) * K + k0 + scol[c], &Bs[(c * 256 + t) * 8]);
        }
        __syncthreads();
#pragma unroll
        for (int ks = 0; ks < 2; ++ks) {
            short8 af[4], bfr[4];
#pragma unroll
            for (int i = 0; i < 4; ++i) {
                const int row = wm + (i << 4) + lm;
                int pb = (row << 7) + (ks << 6) + (lq << 4);
                pb ^= (row & 7) << 4;
                af[i] = *(const short8*)&As[pb >> 1];
            }
#pragma unroll
            for (int j = 0; j < 4; ++j) {
                const int row = wn + (j << 4) + lm;
                int pb = (row << 7) + (ks << 6) + (lq << 4);
                pb ^= (row & 7) << 4;
                bfr[j] = *(const short8*)&Bs[pb >> 1];
            }
#pragma unroll
            for (int i = 0; i < 4; ++i)
#pragma unroll
                for (int j = 0; j < 4; ++j)
                    acc[i][j] = __builtin_amdgcn_mfma_f32_16x16x32_bf16(af[i], bfr[j], acc[i][j], 0, 0, 0);
        }
        __syncthreads();   // final iter: also fences As/Bs before wT_s reuse
    }

    if (cg < 4) {
        // ---- v epilogue: bf16 store, row stride 512
        const int vc0 = cg * 128;
#pragma unroll
        for (int i = 0; i < 4; ++i) {
#pragma unroll
            for (int j = 0; j < 4; ++j) {
                const int gr = row0 + wm + (i << 4) + (lq << 2);
                const int cl = wn + (j << 4) + lm;
                const float bv = wkv_b[512 + vc0 + cl];
#pragma unroll
                for (int r = 0; r < 4; ++r)
                    vout[(size_t)(gr + r) * 512 + vc0 + cl] = f2bf(acc[i][j][r] + bv);
            }
        }
        return;
    }

    // ---- score epilogue (R6 k_scoreg verbatim, xc = cg-4)
    const int xc = cg - 4;
    const int col0 = xc * 128;
    const int b = row0 >> 14;
    const int nb = row0 & 16383;
    float be[4], alf[2];
#pragma unroll
    for (int j = 0; j < 4; ++j) be[j] = beff[col0 + wn + (j << 4) + lm];
#pragma unroll
    for (int hh = 0; hh < 2; ++hh) alf[hh] = alpha[xc * 4 + (w & 1) * 2 + hh];

#pragma unroll
    for (int i = 0; i < 4; ++i)
#pragma unroll
        for (int r = 0; r < 4; ++r)
#pragma unroll
            for (int hh = 0; hh < 2; ++hh) {
                float v0 = (acc[i][2 * hh][r] + be[2 * hh]) * alf[hh];
                float v1 = (acc[i][2 * hh + 1][r] + be[2 * hh + 1]) * alf[hh];
                float mx = fmaxf(v0, v1);
#pragma unroll
                for (int d2 = 1; d2 < 16; d2 <<= 1) mx = fmaxf(mx, __shfl_xor(mx, d2));
                float e0 = __expf(v0 - mx), e1 = __expf(v1 - mx);
                float sm = e0 + e1;
#pragma unroll
                for (int d2 = 1; d2 < 16; d2 <<= 1) sm += __shfl_xor(sm, d2);
                float inv = 1.f / sm;
                acc[i][2 * hh][r] = e0 * inv;
                acc[i][2 * hh + 1][r] = e1 * inv;
            }

    float wsj[4] = {0.f, 0.f, 0.f, 0.f};
#pragma unroll
    for (int i = 0; i < 4; ++i) {
        const int tokb = wm + (i << 4) + (lq << 2);
#pragma unroll
        for (int j = 0; j < 4; ++j) {
            const int h = xc * 4 + (w & 1) * 2 + (j >> 1);
            const int m = ((j & 1) << 4) + lm;
            f32x4 vv = acc[i][j];
            *(f32x4*)(sw_out + ((size_t)((b * 8 + h) * 32 + m)) * N_ + nb + tokb) = vv;
            wsj[j] += vv[0] + vv[1] + vv[2] + vv[3];
            const int c = wn + (j << 4) + lm;
            unsigned lo = pack2(vv[0], vv[1]);
            unsigned hi = pack2(vv[2], vv[3]);
            *(uint2*)(wT_s + c * 128 + (tokb ^ ((c & 7) << 3))) = make_uint2(lo, hi);
        }
    }
#pragma unroll
    for (int j = 0; j < 4; ++j) {
        wsj[j] += __shfl_xor(wsj[j], 16);
        wsj[j] += __shfl_xor(wsj[j], 32);
    }
    if (L < 16) {
        const int panel = nb >> 7;
#pragma unroll
        for (int hh = 0; hh < 2; ++hh) {
            const int h = xc * 4 + (w & 1) * 2 + hh;
            float* pw = pws + (((size_t)((b * 8 + h) * 128 + panel)) * 2 + (w >> 1)) * 32;
            pw[lm] = wsj[2 * hh];
            pw[16 + lm] = wsj[2 * hh + 1];
        }
    }
    __syncthreads();

    // swT emit: thread t -> token t&127, col-chunk (t>>7)*64..+63
    const int tok = t & 127, ch = t >> 7;
    short8* swtp = (short8*)(swT + ((size_t)(b * N_ + nb + tok)) * 256 + xc * 128 + ch * 64);
#pragma unroll
    for (int q = 0; q < 8; ++q) {
        short8 v;
#pragma unroll
        for (int e = 0; e < 8; ++e) {
            const int c = ch * 64 + q * 8 + e;
            v[e] = wT_s[c * 128 + (tok ^ ((c & 7) << 3))];
        }
        swtp[q] = v;
    }
}

// ---------------------------------------------------------------- wsum kernel
// Stages wT_s from swT (bf16) and xvT from v-buffer; num = wT(32x256).xvT^T(256x64)
// via mfma K=256; partials -> pnum.
__global__ __attribute__((amdgpu_flat_work_group_size(256, 256), amdgpu_waves_per_eu(3, 3)))
void k_wsum(const short* __restrict__ v, const short* __restrict__ swT,
            float* __restrict__ pnum) {
    __shared__ __attribute__((aligned(16))) short wT_s[M_ * 256];    // 16 KB [m][n^swz(m)]
    __shared__ __attribute__((aligned(16))) short xvT_s[D_ * 256];   // 32 KB [d][n^swz(d)]
    const int t = threadIdx.x;
    const int bx = blockIdx.x;
    const int chunk = bx & 63;
    const int h = (bx >> 6) & 7;
    const int b = bx >> 9;
    const int w = t >> 6;
    const int L = t & 63;
    const int lm = L & 15;
    const int g = L >> 4;
    const int n0 = chunk * 256;
    const size_t rowb = (size_t)(b * N_ + n0);

    // xv row for token n0+t -> regs (v-only buffer, row stride 512)
    short8 xv8[8];
    const short8* xvp = (const short8*)(v + (rowb + t) * 512 + h * 64);
#pragma unroll
    for (int i = 0; i < 8; ++i) xv8[i] = xvp[i];

    // w row for token n0+t -> regs (64B per thread, each line fully used)
    short8 sw4[4];
    const short8* swp = (const short8*)(swT + (rowb + t) * 256 + h * 32);
#pragma unroll
    for (int q = 0; q < 4; ++q) sw4[q] = swp[q];

    // scatter to wT_s[m][n^swz(m)]: per fixed m, 64 lanes hit 32 banks 2-way (free)
#pragma unroll
    for (int q = 0; q < 4; ++q)
#pragma unroll
        for (int j = 0; j < 8; ++j) {
            const int m = q * 8 + j;
            wT_s[m * 256 + (t ^ ((m & 7) << 3))] = sw4[q][j];
        }

    // xvT transpose write: thread t = token, d = i*8+j, swz granule 8 shorts
#pragma unroll
    for (int i = 0; i < 8; ++i)
#pragma unroll
        for (int j = 0; j < 8; ++j)
            xvT_s[(i * 8 + j) * 256 + (t ^ (j << 3))] = xv8[i][j];

    __syncthreads();

    // phase 2: wave w owns d-cols [w*16, w*16+16), K = 256 tokens
    const int dcol = w * 16 + lm;
    f32x4 acc2[2];
    acc2[0] = (f32x4){0.f, 0.f, 0.f, 0.f};
    acc2[1] = (f32x4){0.f, 0.f, 0.f, 0.f};
#pragma unroll
    for (int ks = 0; ks < 8; ++ks) {
        const int kb = ks * 32 + g * 8;
        short8 bv = *(const short8*)(xvT_s + dcol * 256 + (kb ^ ((lm & 7) << 3)));
#pragma unroll
        for (int mt = 0; mt < 2; ++mt) {
            const int m = mt * 16 + lm;
            short8 av = *(const short8*)(wT_s + m * 256 + (kb ^ ((lm & 7) << 3)));
            acc2[mt] = __builtin_amdgcn_mfma_f32_16x16x32_bf16(av, bv, acc2[mt], 0, 0, 0);
        }
    }

    // per-block partials (non-atomic). num D-layout: row m = mt*16+g*4+r, col dcol.
    float* pn = pnum + ((size_t)((b * 8 + h) * 64 + chunk)) * 2048;
#pragma unroll
    for (int mt = 0; mt < 2; ++mt)
#pragma unroll
        for (int r = 0; r < 4; ++r)
            pn[(mt * 16 + g * 4 + r) * 64 + dcol] = acc2[mt][r];
}

// ------------------- fold partials: num (blocks 0-255), wsum (blocks 256-259)
__global__ __launch_bounds__(256)
void k_reduce(const float* __restrict__ pnum, const float* __restrict__ pws,
              float* __restrict__ num, float* __restrict__ wsum) {
    const int bid = blockIdx.x, t = threadIdx.x;
    if (bid < 256) {
        int e = bid * 256 + t;              // (bh, m*64+d)
        int bh = e >> 11, md = e & 2047;
        const float* p = pnum + (size_t)bh * 64 * 2048 + md;
        float s = 0.f;
#pragma unroll 4
        for (int c = 0; c < 64; ++c) s += p[c * 2048];
        num[e] = s;
    } else {
        int e = (bid - 256) * 256 + t;      // (bh, m), 1024 total
        int bh = e >> 5, m = e & 31;
        const float* p = pws + (size_t)bh * 8192 + m;   // 128 panels x 2 wave-groups
        float s = 0.f;
#pragma unroll 4
        for (int cw = 0; cw < 256; ++cw) s += p[cw * 32];
        wsum[e] = s;
    }
}

// ---------------------------------------------------------------- qkv GEMM (tiny)
__global__ __launch_bounds__(256, 2)
void k_qkv(const float* __restrict__ num, const float* __restrict__ wsum,
           const float* __restrict__ qkv_w, float* __restrict__ qkv) {
    __shared__ float st_s[512 * 32];  // [k][m], 64 KB
    const int t = threadIdx.x;
    const int b = blockIdx.y;
    for (int p = 0; p < 64; ++p) {
        int idx = p * 256 + t;
        int m = idx & 31, k = idx >> 5;
        int h = k >> 6, d = k & 63;
        float wsv = wsum[(b * H_ + h) * M_ + m];
        st_s[k * 32 + m] = num[((size_t)(b * H_ + h) * M_ + m) * 64 + d] / (wsv + 1e-5f);
    }
    __syncthreads();
    const int m = t >> 3;
    const int c0 = blockIdx.x * 64 + (t & 7) * 8;
    float acc[8] = {};
    for (int k = 0; k < 512; ++k) {
        float sv = st_s[k * 32 + m];
        const f32x4* wp = (const f32x4*)(qkv_w + (size_t)k * 1536 + c0);
        f32x4 w0 = wp[0], w1 = wp[1];
        acc[0] += sv * w0[0]; acc[1] += sv * w0[1]; acc[2] += sv * w0[2]; acc[3] += sv * w0[3];
        acc[4] += sv * w1[0]; acc[5] += sv * w1[1]; acc[6] += sv * w1[2]; acc[7] += sv * w1[3];
    }
    float* dst = qkv + (size_t)(b * M_ + m) * 1536 + c0;
#pragma unroll
    for (int i = 0; i < 8; ++i) dst[i] = acc[i];
}

// ---------------------------------------------------------------- MHA (tiny, M=32)
__global__ __launch_bounds__(256)
void k_mha(const float* __restrict__ qkv, float* __restrict__ attn_out,
           float* __restrict__ ot) {
    __shared__ float q_s[32 * 65], k_s[32 * 65], v_s[32 * 65];
    __shared__ float s_s[32 * 33], p_s[32 * 33];
    const int bx = blockIdx.x;
    const int b = bx >> 3, h = bx & 7;
    const int t = threadIdx.x;
    for (int p = 0; p < 8; ++p) {
        int idx = p * 256 + t;
        int m = idx >> 6, d = idx & 63;
        size_t base = (size_t)(b * M_ + m) * 1536 + h * 64 + d;
        q_s[m * 65 + d] = qkv[base];
        k_s[m * 65 + d] = qkv[base + 512];
        v_s[m * 65 + d] = qkv[base + 1024];
    }
    __syncthreads();
    for (int p = 0; p < 4; ++p) {
        int c = p * 256 + t;
        int m = c >> 5, mm = c & 31;
        float a = 0.f;
#pragma unroll
        for (int d = 0; d < 64; ++d) a += q_s[m * 65 + d] * k_s[mm * 65 + d];
        s_s[m * 33 + mm] = a * 0.125f;
    }
    __syncthreads();
    if (t < 32) {
        float mx = -1e30f;
        for (int mm = 0; mm < 32; ++mm) mx = fmaxf(mx, s_s[t * 33 + mm]);
        float sum = 0.f;
        for (int mm = 0; mm < 32; ++mm) {
            float e = __expf(s_s[t * 33 + mm] - mx);
            p_s[t * 33 + mm] = e;
            sum += e;
        }
        float inv = 1.f / sum;
        for (int mm = 0; mm < 32; ++mm) {
            float av = p_s[t * 33 + mm] * inv;
            p_s[t * 33 + mm] = av;
            attn_out[((size_t)(b * H_ + h) * M_ + t) * M_ + mm] = av;
        }
    }
    __syncthreads();
    const int m = t >> 3, d0 = (t & 7) * 8;
    float acc[8] = {};
    for (int mm = 0; mm < 32; ++mm) {
        float av = p_s[m * 33 + mm];
#pragma unroll
        for (int j = 0; j < 8; ++j) acc[j] += av * v_s[mm * 65 + d0 + j];
    }
    float* dst = ot + ((size_t)(b * H_ + h) * M_ + m) * 64 + d0;
#pragma unroll
    for (int j = 0; j < 8; ++j) dst[j] = acc[j];
}

// ------------------------------------- P^T: Pt[b][j][h*32+m]
__global__ __launch_bounds__(256)
void k_p(const float* __restrict__ ot, const float* __restrict__ out_w,
         short* __restrict__ Pt) {
    __shared__ float ot_s[32 * 65];
    const int bh = blockIdx.y;
    const int b = bh >> 3, h = bh & 7;
    const int t = threadIdx.x;
    for (int p = 0; p < 8; ++p) {
        int idx = p * 256 + t;
        int m = idx >> 6, d = idx & 63;
        ot_s[m * 65 + d] = ot[(size_t)bh * (M_ * 64) + idx];
    }
    __syncthreads();
    const int j = blockIdx.x * 128 + (t & 127);
    const int mh = (t >> 7) * 16;
    float acc[16] = {};
    for (int d = 0; d < 64; ++d) {
        float ow = out_w[(size_t)(h * 64 + d) * HID_ + j];
#pragma unroll
        for (int i = 0; i < 16; ++i) acc[i] += ot_s[(mh + i) * 65 + d] * ow;
    }
    short* dst = Pt + ((size_t)b * HID_ + j) * (H_ * M_) + h * M_ + mh;
#pragma unroll
    for (int i = 0; i < 16; i += 2) *(unsigned*)(dst + i) = pack2(acc[i], acc[i + 1]);
}

// ---------------------------------------------------------------- launcher
extern "C" void kernel_launch(void* const* d_in, const int* in_sizes, int n_in,
                              void* d_out, int out_size, void* d_ws, size_t ws_size,
                              hipStream_t stream) {
    const float* x     = (const float*)d_in[0];
    const float* wkv_w = (const float*)d_in[1];
    const float* wkv_b = (const float*)d_in[2];
    const float* wtq   = (const float*)d_in[3];
    const float* alpha = (const float*)d_in[4];
    const float* qkv_w = (const float*)d_in[5];
    const float* out_w = (const float*)d_in[6];
    const float* out_b = (const float*)d_in[7];

    float* out       = (float*)d_out;
    float* sw_out    = out + (size_t)B_ * N_ * HID_;                // 33,554,432
    float* alpha_out = sw_out + (size_t)B_ * H_ * M_ * N_;          // 50,331,648
    float* zeros_out = alpha_out + H_;                              // 50,331,656
    float* attn_out  = zeros_out + H_ * M_;                         // 50,331,912

    // partials overlay the `out` region (dead until final GEMM writes it last):
    float* pnum = out;                                              // 16 MB (32*64*2048 f32)
    float* pws  = out + 4194304;                                    //  1 MB (32*128*2*32 f32)

    char* ws = (char*)d_ws;
    short* v    = (short*)(ws);                //  67,108,864 B  (B,N,512)   bf16 (v only)
    short* x_bf = (short*)(ws + 67108864);     //  67,108,864 B  (B,N,HID)   bf16
    short* swT  = (short*)(ws + 134217728);    //  33,554,432 B  (B,N,H*M)   bf16
    short* wkvT = (short*)(ws + 167772160);    //   1,048,576 B  (rows 512-1023 used)
    short* Pt   = (short*)(ws + 168820736);    //   1,048,576 B  (B,512,256) bf16
    float* num  = (float*)(ws + 169869312);    //     262,144 B  (B,H,M,64)  f32
    float* wsum = (float*)(ws + 170131456);    //       4,096 B  (B,H,M)     f32
    float* qkvb = (float*)(ws + 170135552);    //     786,432 B  (B,M,1536)  f32
    float* ot   = (float*)(ws + 170921984);    //     262,144 B  (B,H,M,64)  f32
    // WeffT overlays ot (dead until k_mha; k_vs reads it before that).
    short* WeffT = (short*)(ws + 170921984);   //     262,144 B  (256,512)   bf16
    // beff overlays wsum (k_reduce writes wsum after k_vs reads beff).
    float* beff  = (float*)(ws + 170131456);   //       1,024 B  (256)       f32

    k_cvt<<<16384, 256, 0, stream>>>(x, x_bf);
    k_prep<<<320, 256, 0, stream>>>(alpha, alpha_out, zeros_out,
                                    wkv_w, wkv_b, wtq, WeffT, beff, wkvT);
    // merged: v = (x@wkv_w+b)[:,512:]  AND  scores+softmax+sw_out+swT+pws
    k_vs<<<3072, 256, 0, stream>>>(x_bf, wkvT + 512 * 512, wkv_b, WeffT, beff,
                                   alpha, v, sw_out, swT, pws);
    k_wsum<<<2048, 256, 0, stream>>>(v, swT, pnum);
    k_reduce<<<260, 256, 0, stream>>>(pnum, pws, num, wsum);
    k_qkv<<<dim3(24, 4), 256, 0, stream>>>(num, wsum, qkv_w, qkvb);
    k_mha<<<32, 256, 0, stream>>>(qkvb, attn_out, ot);
    k_p<<<dim3(4, 32), 256, 0, stream>>>(ot, out_w, Pt);
    // out = swT @ Pt^T + out_b   (f32 out)
    mfma_gemm<false><<<dim3(4, 512), 256, 0, stream>>>(
        swT, Pt, out_b, (void*)out, 256, 512, 131072, 16384, 2);
}

// Round 8
// 527.926 us; speedup vs baseline: 1.0578x; 1.0578x over previous
//
#include <hip/hip_runtime.h>

#define B_ 4
#define N_ 16384
#define HID_ 512
#define H_ 8
#define M_ 32
#define D_ 64

typedef __attribute__((ext_vector_type(8))) short short8;
typedef __attribute__((ext_vector_type(4))) float f32x4;

__device__ __forceinline__ short f2bf(float f) {
    unsigned u = __float_as_uint(f);
    u += 0x7fffu + ((u >> 16) & 1u);
    return (short)(u >> 16);
}
__device__ __forceinline__ float bf2f(short s) {
    return __uint_as_float(((unsigned)(unsigned short)s) << 16);
}
__device__ __forceinline__ unsigned pack2(float a, float b) {
    return (unsigned)(unsigned short)f2bf(a) | ((unsigned)(unsigned short)f2bf(b) << 16);
}
__device__ __forceinline__ void gl_lds16(const short* g, short* l) {
    __builtin_amdgcn_global_load_lds((const __attribute__((address_space(1))) unsigned*)g,
                                     (__attribute__((address_space(3))) unsigned*)l, 16, 0, 0);
}

// --------------------------------------------- x (f32) -> bf16, streaming convert
__global__ void k_cvt(const float* __restrict__ src, short* __restrict__ dst) {
    int i = blockIdx.x * 256 + threadIdx.x;   // 8 elements per thread
    const f32x4* s = (const f32x4*)(src) + (size_t)i * 2;
    f32x4 a = s[0], b = s[1];
    short8 o;
    o[0] = f2bf(a[0]); o[1] = f2bf(a[1]); o[2] = f2bf(a[2]); o[3] = f2bf(a[3]);
    o[4] = f2bf(b[0]); o[5] = f2bf(b[1]); o[6] = f2bf(b[2]); o[7] = f2bf(b[3]);
    ((short8*)dst)[i] = o;
}

// ---------------- prep: blocks 0-255 = Weff fold (+ misc outputs in block 0);
//                  blocks 256-319 = wkv_w v-half transpose (64x64 LDS tiles).
// Weff = Wk.wtq^T: scores = (x@Wk+bk).wtq^T = x@Weff + beff (exact algebra,
// f32 accumulate, single bf16 rounding). R7-verified; kept from R7 (launch saving
// only - no resource interaction).
__global__ __launch_bounds__(256)
void k_prep(const float* __restrict__ alpha, float* __restrict__ a_out,
            float* __restrict__ z_out, const float* __restrict__ wkv_w,
            const float* __restrict__ wkv_b, const float* __restrict__ wtq,
            short* __restrict__ WeffT, float* __restrict__ beff,
            short* __restrict__ wt) {
    const int bid = blockIdx.x, t = threadIdx.x;
    if (bid < 256) {
        __shared__ float wq_s[64];
        const int c = bid;          // h*32+m
        const int h = c >> 5;
        if (t < 64) wq_s[t] = wtq[c * 64 + t];
        __syncthreads();
#pragma unroll
        for (int kk = 0; kk < 2; ++kk) {
            const int k = kk * 256 + t;
            const float* wr = wkv_w + (size_t)k * 1024 + h * 64;
            float a = 0.f;
#pragma unroll
            for (int d = 0; d < 64; ++d) a += wr[d] * wq_s[d];
            WeffT[c * 512 + k] = f2bf(a);    // coalesced across t
        }
        if (t == 0) {
            float a = 0.f;
            for (int d = 0; d < 64; ++d) a += wkv_b[h * 64 + d] * wq_s[d];
            beff[c] = a;
        }
        if (bid == 0) {
            if (t < H_) a_out[t] = alpha[t];
            z_out[t] = 0.f;  // 256 = H_*M_
        }
    } else {
        __shared__ float ls[64][65];
        const int b2 = bid - 256;
        const int n0 = ((b2 & 7) + 8) * 64, k0 = (b2 >> 3) * 64;
#pragma unroll
        for (int p = 0; p < 16; ++p) {
            int idx = p * 256 + t;
            int kk = idx >> 6, nn = idx & 63;
            ls[kk][nn] = wkv_w[(size_t)(k0 + kk) * 1024 + n0 + nn];
        }
        __syncthreads();
#pragma unroll
        for (int p = 0; p < 16; ++p) {
            int idx = p * 256 + t;
            int nn = idx >> 6, kk = idx & 63;
            wt[(size_t)(n0 + nn) * 512 + k0 + kk] = f2bf(ls[kk][nn]);
        }
    }
}

// ------------------------------------- MFMA GEMM (m97 + XCD swz + BK=64 + T2 swz)
// R7's merged k_vs REVERTED: occupancy 26->17% + role imbalance; FETCH unchanged
// (x_bf was already L3-resident across dispatches - fusion bought nothing).
// Used for: v = x@Wv + bv (grid (4,512)) and out = swT@Pt^T + out_b (grid (4,512)).
template <bool OUT_BF16>
__global__ __launch_bounds__(256, 2)
void mfma_gemm(const short* __restrict__ A, const short* __restrict__ Bt,
               const float* __restrict__ bias, void* __restrict__ Cv,
               int K, int Ncols, int b_stride, int rows_per_b, int lgx) {
    __shared__ short As[128 * 64];
    __shared__ short Bs[128 * 64];
    const int t = threadIdx.x;
    const int nwg = gridDim.x * gridDim.y;
    int id = blockIdx.y * gridDim.x + blockIdx.x;
    id = (id & 7) * (nwg >> 3) + (id >> 3);
    const int col0 = (id & ((1 << lgx) - 1)) * 128;
    const int row0 = (id >> lgx) * 128;
    const short* Bblk = Bt;
    if (b_stride) Bblk += (size_t)(row0 / rows_per_b) * (size_t)b_stride;

    int srow[4], scol[4];
#pragma unroll
    for (int c = 0; c < 4; ++c) {
        int lin = (c * 256 + t) * 16;
        int logo = lin ^ (((lin >> 7) & 7) << 4);
        srow[c] = logo >> 7;
        scol[c] = (logo & 127) >> 1;   // shorts
    }

    const int w = t >> 6;
    const int L = t & 63;
    const int wm = (w >> 1) << 6;
    const int wn = (w & 1) << 6;
    const int lm = L & 15;
    const int lq = L >> 4;

    f32x4 acc[4][4];
#pragma unroll
    for (int i = 0; i < 4; ++i)
#pragma unroll
        for (int j = 0; j < 4; ++j) acc[i][j] = (f32x4){0.f, 0.f, 0.f, 0.f};

    for (int k0 = 0; k0 < K; k0 += 64) {
#pragma unroll
        for (int c = 0; c < 4; ++c) {
            gl_lds16(A + (size_t)(row0 + srow[c]) * K + k0 + scol[c], &As[(c * 256 + t) * 8]);
            gl_lds16(Bblk + (size_t)(col0 + srow[c]) * K + k0 + scol[c], &Bs[(c * 256 + t) * 8]);
        }
        __syncthreads();
#pragma unroll
        for (int ks = 0; ks < 2; ++ks) {
            short8 af[4], bfr[4];
#pragma unroll
            for (int i = 0; i < 4; ++i) {
                const int row = wm + (i << 4) + lm;
                int pb = (row << 7) + (ks << 6) + (lq << 4);
                pb ^= (row & 7) << 4;
                af[i] = *(const short8*)&As[pb >> 1];
            }
#pragma unroll
            for (int j = 0; j < 4; ++j) {
                const int row = wn + (j << 4) + lm;
                int pb = (row << 7) + (ks << 6) + (lq << 4);
                pb ^= (row & 7) << 4;
                bfr[j] = *(const short8*)&Bs[pb >> 1];
            }
#pragma unroll
            for (int i = 0; i < 4; ++i)
#pragma unroll
                for (int j = 0; j < 4; ++j)
                    acc[i][j] = __builtin_amdgcn_mfma_f32_16x16x32_bf16(af[i], bfr[j], acc[i][j], 0, 0, 0);
        }
        __syncthreads();
    }
#pragma unroll
    for (int i = 0; i < 4; ++i) {
#pragma unroll
        for (int j = 0; j < 4; ++j) {
            const int gr = row0 + wm + (i << 4) + (lq << 2);
            const int gc = col0 + wn + (j << 4) + lm;
            const float bv = bias[gc];
#pragma unroll
            for (int r = 0; r < 4; ++r) {
                float v = acc[i][j][r] + bv;
                if constexpr (OUT_BF16)
                    ((short*)Cv)[(size_t)(gr + r) * Ncols + gc] = f2bf(v);
                else
                    ((float*)Cv)[(size_t)(gr + r) * Ncols + gc] = v;
            }
        }
    }
}

// ---------------------------- fused score GEMM: S = x_bf @ WeffT^T + beff, K=512
// 128x128 tile (128 tokens x 4 heads). Main loop = mfma_gemm verbatim.
// Epilogue: softmax over m in-register (16-lane shfl_xor), sw_out full-line f32x4
// stores, swT via XOR-swizzled wT_s (reuses As/Bs LDS after final barrier), pws.
// R6-measured kernel, reverted verbatim.
__global__ __launch_bounds__(256, 2)
void k_scoreg(const short* __restrict__ A, const short* __restrict__ WeffT,
              const float* __restrict__ beff, const float* __restrict__ alpha,
              float* __restrict__ sw_out, short* __restrict__ swT,
              float* __restrict__ pws) {
    __shared__ __attribute__((aligned(16))) short smem[16384];  // 32 KB
    short* As = smem;              // 128x64 (main loop)
    short* Bs = smem + 8192;       // 128x64 (main loop)
    short* wT_s = smem;            // [128 col][128 tok], reused after loop
    const int t = threadIdx.x;
    int id = blockIdx.y * 2 + blockIdx.x;
    id = (id & 7) * 128 + (id >> 3);          // XCD swizzle, nwg=1024
    const int xc = id & 1;
    const int row0 = (id >> 1) * 128;
    const int col0 = xc * 128;
    const int K = 512;

    int srow[4], scol[4];
#pragma unroll
    for (int c = 0; c < 4; ++c) {
        int lin = (c * 256 + t) * 16;
        int logo = lin ^ (((lin >> 7) & 7) << 4);
        srow[c] = logo >> 7;
        scol[c] = (logo & 127) >> 1;
    }
    const int w = t >> 6;
    const int L = t & 63;
    const int wm = (w >> 1) << 6;
    const int wn = (w & 1) << 6;
    const int lm = L & 15;
    const int lq = L >> 4;

    f32x4 acc[4][4];
#pragma unroll
    for (int i = 0; i < 4; ++i)
#pragma unroll
        for (int j = 0; j < 4; ++j) acc[i][j] = (f32x4){0.f, 0.f, 0.f, 0.f};

    for (int k0 = 0; k0 < K; k0 += 64) {
#pragma unroll
        for (int c = 0; c < 4; ++c) {
            gl_lds16(A + (size_t)(row0 + srow[c]) * K + k0 + scol[c], &As[(c * 256 + t) * 8]);
            gl_lds16(WeffT + (size_t)(col0 + srow[c]) * K + k0 + scol[c], &Bs[(c * 256 + t) * 8]);
        }
        __syncthreads();
#pragma unroll
        for (int ks = 0; ks < 2; ++ks) {
            short8 af[4], bfr[4];
#pragma unroll
            for (int i = 0; i < 4; ++i) {
                const int row = wm + (i << 4) + lm;
                int pb = (row << 7) + (ks << 6) + (lq << 4);
                pb ^= (row & 7) << 4;
                af[i] = *(const short8*)&As[pb >> 1];
            }
#pragma unroll
            for (int j = 0; j < 4; ++j) {
                const int row = wn + (j << 4) + lm;
                int pb = (row << 7) + (ks << 6) + (lq << 4);
                pb ^= (row & 7) << 4;
                bfr[j] = *(const short8*)&Bs[pb >> 1];
            }
#pragma unroll
            for (int i = 0; i < 4; ++i)
#pragma unroll
                for (int j = 0; j < 4; ++j)
                    acc[i][j] = __builtin_amdgcn_mfma_f32_16x16x32_bf16(af[i], bfr[j], acc[i][j], 0, 0, 0);
        }
        __syncthreads();   // also fences As/Bs before wT_s reuse
    }

    // ---- epilogue: bias, alpha, softmax over m (16-lane shfl per head)
    const int b = row0 >> 14;
    const int nb = row0 & 16383;
    float be[4], alf[2];
#pragma unroll
    for (int j = 0; j < 4; ++j) be[j] = beff[col0 + wn + (j << 4) + lm];
#pragma unroll
    for (int hh = 0; hh < 2; ++hh) alf[hh] = alpha[xc * 4 + (w & 1) * 2 + hh];

#pragma unroll
    for (int i = 0; i < 4; ++i)
#pragma unroll
        for (int r = 0; r < 4; ++r)
#pragma unroll
            for (int hh = 0; hh < 2; ++hh) {
                float v0 = (acc[i][2 * hh][r] + be[2 * hh]) * alf[hh];
                float v1 = (acc[i][2 * hh + 1][r] + be[2 * hh + 1]) * alf[hh];
                float mx = fmaxf(v0, v1);
#pragma unroll
                for (int d2 = 1; d2 < 16; d2 <<= 1) mx = fmaxf(mx, __shfl_xor(mx, d2));
                float e0 = __expf(v0 - mx), e1 = __expf(v1 - mx);
                float sm = e0 + e1;
#pragma unroll
                for (int d2 = 1; d2 < 16; d2 <<= 1) sm += __shfl_xor(sm, d2);
                float inv = 1.f / sm;
                acc[i][2 * hh][r] = e0 * inv;
                acc[i][2 * hh + 1][r] = e1 * inv;
            }

    // ---- sw_out stores (full 64B lines) + wT_s + wsum partials
    float wsj[4] = {0.f, 0.f, 0.f, 0.f};
#pragma unroll
    for (int i = 0; i < 4; ++i) {
        const int tokb = wm + (i << 4) + (lq << 2);
#pragma unroll
        for (int j = 0; j < 4; ++j) {
            const int h = xc * 4 + (w & 1) * 2 + (j >> 1);
            const int m = ((j & 1) << 4) + lm;
            f32x4 vv = acc[i][j];
            *(f32x4*)(sw_out + ((size_t)((b * 8 + h) * 32 + m)) * N_ + nb + tokb) = vv;
            wsj[j] += vv[0] + vv[1] + vv[2] + vv[3];
            const int c = wn + (j << 4) + lm;
            unsigned lo = pack2(vv[0], vv[1]);
            unsigned hi = pack2(vv[2], vv[3]);
            *(uint2*)(wT_s + c * 128 + (tokb ^ ((c & 7) << 3))) = make_uint2(lo, hi);
        }
    }
#pragma unroll
    for (int j = 0; j < 4; ++j) {
        wsj[j] += __shfl_xor(wsj[j], 16);
        wsj[j] += __shfl_xor(wsj[j], 32);
    }
    if (L < 16) {
        const int panel = nb >> 7;
#pragma unroll
        for (int hh = 0; hh < 2; ++hh) {
            const int h = xc * 4 + (w & 1) * 2 + hh;
            float* pw = pws + (((size_t)((b * 8 + h) * 128 + panel)) * 2 + (w >> 1)) * 32;
            pw[lm] = wsj[2 * hh];
            pw[16 + lm] = wsj[2 * hh + 1];
        }
    }
    __syncthreads();

    // ---- swT emit: thread t -> token t&127, col-chunk (t>>7)*64..+63
    const int tok = t & 127, ch = t >> 7;
    short8* swtp = (short8*)(swT + ((size_t)(b * N_ + nb + tok)) * 256 + xc * 128 + ch * 64);
#pragma unroll
    for (int q = 0; q < 8; ++q) {
        short8 v;
#pragma unroll
        for (int e = 0; e < 8; ++e) {
            const int c = ch * 64 + q * 8 + e;
            v[e] = wT_s[c * 128 + (tok ^ ((c & 7) << 3))];
        }
        swtp[q] = v;
    }
}

// ---------------------------------------------------------------- wsum kernel
// Stages wT_s from swT (bf16) and xvT from v-buffer; num = wT(32x256).xvT^T(256x64)
// via mfma K=256; partials -> pnum.
__global__ __attribute__((amdgpu_flat_work_group_size(256, 256), amdgpu_waves_per_eu(3, 3)))
void k_wsum(const short* __restrict__ v, const short* __restrict__ swT,
            float* __restrict__ pnum) {
    __shared__ __attribute__((aligned(16))) short wT_s[M_ * 256];    // 16 KB [m][n^swz(m)]
    __shared__ __attribute__((aligned(16))) short xvT_s[D_ * 256];   // 32 KB [d][n^swz(d)]
    const int t = threadIdx.x;
    const int bx = blockIdx.x;
    const int chunk = bx & 63;
    const int h = (bx >> 6) & 7;
    const int b = bx >> 9;
    const int w = t >> 6;
    const int L = t & 63;
    const int lm = L & 15;
    const int g = L >> 4;
    const int n0 = chunk * 256;
    const size_t rowb = (size_t)(b * N_ + n0);

    // xv row for token n0+t -> regs (v-only buffer, row stride 512)
    short8 xv8[8];
    const short8* xvp = (const short8*)(v + (rowb + t) * 512 + h * 64);
#pragma unroll
    for (int i = 0; i < 8; ++i) xv8[i] = xvp[i];

    // w row for token n0+t -> regs (64B per thread, each line fully used)
    short8 sw4[4];
    const short8* swp = (const short8*)(swT + (rowb + t) * 256 + h * 32);
#pragma unroll
    for (int q = 0; q < 4; ++q) sw4[q] = swp[q];

    // scatter to wT_s[m][n^swz(m)]: per fixed m, 64 lanes hit 32 banks 2-way (free)
#pragma unroll
    for (int q = 0; q < 4; ++q)
#pragma unroll
        for (int j = 0; j < 8; ++j) {
            const int m = q * 8 + j;
            wT_s[m * 256 + (t ^ ((m & 7) << 3))] = sw4[q][j];
        }

    // xvT transpose write: thread t = token, d = i*8+j, swz granule 8 shorts
#pragma unroll
    for (int i = 0; i < 8; ++i)
#pragma unroll
        for (int j = 0; j < 8; ++j)
            xvT_s[(i * 8 + j) * 256 + (t ^ (j << 3))] = xv8[i][j];

    __syncthreads();

    // phase 2: wave w owns d-cols [w*16, w*16+16), K = 256 tokens
    const int dcol = w * 16 + lm;
    f32x4 acc2[2];
    acc2[0] = (f32x4){0.f, 0.f, 0.f, 0.f};
    acc2[1] = (f32x4){0.f, 0.f, 0.f, 0.f};
#pragma unroll
    for (int ks = 0; ks < 8; ++ks) {
        const int kb = ks * 32 + g * 8;
        short8 bv = *(const short8*)(xvT_s + dcol * 256 + (kb ^ ((lm & 7) << 3)));
#pragma unroll
        for (int mt = 0; mt < 2; ++mt) {
            const int m = mt * 16 + lm;
            short8 av = *(const short8*)(wT_s + m * 256 + (kb ^ ((lm & 7) << 3)));
            acc2[mt] = __builtin_amdgcn_mfma_f32_16x16x32_bf16(av, bv, acc2[mt], 0, 0, 0);
        }
    }

    // per-block partials (non-atomic). num D-layout: row m = mt*16+g*4+r, col dcol.
    float* pn = pnum + ((size_t)((b * 8 + h) * 64 + chunk)) * 2048;
#pragma unroll
    for (int mt = 0; mt < 2; ++mt)
#pragma unroll
        for (int r = 0; r < 4; ++r)
            pn[(mt * 16 + g * 4 + r) * 64 + dcol] = acc2[mt][r];
}

// ------------------- fold partials: num (blocks 0-255), wsum (blocks 256-259)
__global__ __launch_bounds__(256)
void k_reduce(const float* __restrict__ pnum, const float* __restrict__ pws,
              float* __restrict__ num, float* __restrict__ wsum) {
    const int bid = blockIdx.x, t = threadIdx.x;
    if (bid < 256) {
        int e = bid * 256 + t;              // (bh, m*64+d)
        int bh = e >> 11, md = e & 2047;
        const float* p = pnum + (size_t)bh * 64 * 2048 + md;
        float s = 0.f;
#pragma unroll 4
        for (int c = 0; c < 64; ++c) s += p[c * 2048];
        num[e] = s;
    } else {
        int e = (bid - 256) * 256 + t;      // (bh, m), 1024 total
        int bh = e >> 5, m = e & 31;
        const float* p = pws + (size_t)bh * 8192 + m;   // 128 panels x 2 wave-groups
        float s = 0.f;
#pragma unroll 4
        for (int cw = 0; cw < 256; ++cw) s += p[cw * 32];
        wsum[e] = s;
    }
}

// ---------------------------------------------------------------- qkv GEMM (tiny)
__global__ __launch_bounds__(256, 2)
void k_qkv(const float* __restrict__ num, const float* __restrict__ wsum,
           const float* __restrict__ qkv_w, float* __restrict__ qkv) {
    __shared__ float st_s[512 * 32];  // [k][m], 64 KB
    const int t = threadIdx.x;
    const int b = blockIdx.y;
    for (int p = 0; p < 64; ++p) {
        int idx = p * 256 + t;
        int m = idx & 31, k = idx >> 5;
        int h = k >> 6, d = k & 63;
        float wsv = wsum[(b * H_ + h) * M_ + m];
        st_s[k * 32 + m] = num[((size_t)(b * H_ + h) * M_ + m) * 64 + d] / (wsv + 1e-5f);
    }
    __syncthreads();
    const int m = t >> 3;
    const int c0 = blockIdx.x * 64 + (t & 7) * 8;
    float acc[8] = {};
    for (int k = 0; k < 512; ++k) {
        float sv = st_s[k * 32 + m];
        const f32x4* wp = (const f32x4*)(qkv_w + (size_t)k * 1536 + c0);
        f32x4 w0 = wp[0], w1 = wp[1];
        acc[0] += sv * w0[0]; acc[1] += sv * w0[1]; acc[2] += sv * w0[2]; acc[3] += sv * w0[3];
        acc[4] += sv * w1[0]; acc[5] += sv * w1[1]; acc[6] += sv * w1[2]; acc[7] += sv * w1[3];
    }
    float* dst = qkv + (size_t)(b * M_ + m) * 1536 + c0;
#pragma unroll
    for (int i = 0; i < 8; ++i) dst[i] = acc[i];
}

// ---------------------------------------------------------------- MHA (tiny, M=32)
__global__ __launch_bounds__(256)
void k_mha(const float* __restrict__ qkv, float* __restrict__ attn_out,
           float* __restrict__ ot) {
    __shared__ float q_s[32 * 65], k_s[32 * 65], v_s[32 * 65];
    __shared__ float s_s[32 * 33], p_s[32 * 33];
    const int bx = blockIdx.x;
    const int b = bx >> 3, h = bx & 7;
    const int t = threadIdx.x;
    for (int p = 0; p < 8; ++p) {
        int idx = p * 256 + t;
        int m = idx >> 6, d = idx & 63;
        size_t base = (size_t)(b * M_ + m) * 1536 + h * 64 + d;
        q_s[m * 65 + d] = qkv[base];
        k_s[m * 65 + d] = qkv[base + 512];
        v_s[m * 65 + d] = qkv[base + 1024];
    }
    __syncthreads();
    for (int p = 0; p < 4; ++p) {
        int c = p * 256 + t;
        int m = c >> 5, mm = c & 31;
        float a = 0.f;
#pragma unroll
        for (int d = 0; d < 64; ++d) a += q_s[m * 65 + d] * k_s[mm * 65 + d];
        s_s[m * 33 + mm] = a * 0.125f;
    }
    __syncthreads();
    if (t < 32) {
        float mx = -1e30f;
        for (int mm = 0; mm < 32; ++mm) mx = fmaxf(mx, s_s[t * 33 + mm]);
        float sum = 0.f;
        for (int mm = 0; mm < 32; ++mm) {
            float e = __expf(s_s[t * 33 + mm] - mx);
            p_s[t * 33 + mm] = e;
            sum += e;
        }
        float inv = 1.f / sum;
        for (int mm = 0; mm < 32; ++mm) {
            float av = p_s[t * 33 + mm] * inv;
            p_s[t * 33 + mm] = av;
            attn_out[((size_t)(b * H_ + h) * M_ + t) * M_ + mm] = av;
        }
    }
    __syncthreads();
    const int m = t >> 3, d0 = (t & 7) * 8;
    float acc[8] = {};
    for (int mm = 0; mm < 32; ++mm) {
        float av = p_s[m * 33 + mm];
#pragma unroll
        for (int j = 0; j < 8; ++j) acc[j] += av * v_s[mm * 65 + d0 + j];
    }
    float* dst = ot + ((size_t)(b * H_ + h) * M_ + m) * 64 + d0;
#pragma unroll
    for (int j = 0; j < 8; ++j) dst[j] = acc[j];
}

// ------------------------------------- P^T: Pt[b][j][h*32+m]
__global__ __launch_bounds__(256)
void k_p(const float* __restrict__ ot, const float* __restrict__ out_w,
         short* __restrict__ Pt) {
    __shared__ float ot_s[32 * 65];
    const int bh = blockIdx.y;
    const int b = bh >> 3, h = bh & 7;
    const int t = threadIdx.x;
    for (int p = 0; p < 8; ++p) {
        int idx = p * 256 + t;
        int m = idx >> 6, d = idx & 63;
        ot_s[m * 65 + d] = ot[(size_t)bh * (M_ * 64) + idx];
    }
    __syncthreads();
    const int j = blockIdx.x * 128 + (t & 127);
    const int mh = (t >> 7) * 16;
    float acc[16] = {};
    for (int d = 0; d < 64; ++d) {
        float ow = out_w[(size_t)(h * 64 + d) * HID_ + j];
#pragma unroll
        for (int i = 0; i < 16; ++i) acc[i] += ot_s[(mh + i) * 65 + d] * ow;
    }
    short* dst = Pt + ((size_t)b * HID_ + j) * (H_ * M_) + h * M_ + mh;
#pragma unroll
    for (int i = 0; i < 16; i += 2) *(unsigned*)(dst + i) = pack2(acc[i], acc[i + 1]);
}

// ---------------------------------------------------------------- launcher
extern "C" void kernel_launch(void* const* d_in, const int* in_sizes, int n_in,
                              void* d_out, int out_size, void* d_ws, size_t ws_size,
                              hipStream_t stream) {
    const float* x     = (const float*)d_in[0];
    const float* wkv_w = (const float*)d_in[1];
    const float* wkv_b = (const float*)d_in[2];
    const float* wtq   = (const float*)d_in[3];
    const float* alpha = (const float*)d_in[4];
    const float* qkv_w = (const float*)d_in[5];
    const float* out_w = (const float*)d_in[6];
    const float* out_b = (const float*)d_in[7];

    float* out       = (float*)d_out;
    float* sw_out    = out + (size_t)B_ * N_ * HID_;                // 33,554,432
    float* alpha_out = sw_out + (size_t)B_ * H_ * M_ * N_;          // 50,331,648
    float* zeros_out = alpha_out + H_;                              // 50,331,656
    float* attn_out  = zeros_out + H_ * M_;                         // 50,331,912

    // partials overlay the `out` region (dead until final GEMM writes it last):
    float* pnum = out;                                              // 16 MB (32*64*2048 f32)
    float* pws  = out + 4194304;                                    //  1 MB (32*128*2*32 f32)

    char* ws = (char*)d_ws;
    short* v    = (short*)(ws);                //  67,108,864 B  (B,N,512)   bf16 (v only)
    short* x_bf = (short*)(ws + 67108864);     //  67,108,864 B  (B,N,HID)   bf16
    short* swT  = (short*)(ws + 134217728);    //  33,554,432 B  (B,N,H*M)   bf16
    short* wkvT = (short*)(ws + 167772160);    //   1,048,576 B  (rows 512-1023 used)
    short* Pt   = (short*)(ws + 168820736);    //   1,048,576 B  (B,512,256) bf16
    float* num  = (float*)(ws + 169869312);    //     262,144 B  (B,H,M,64)  f32
    float* wsum = (float*)(ws + 170131456);    //       4,096 B  (B,H,M)     f32
    float* qkvb = (float*)(ws + 170135552);    //     786,432 B  (B,M,1536)  f32
    float* ot   = (float*)(ws + 170921984);    //     262,144 B  (B,H,M,64)  f32
    // WeffT overlays ot (dead until k_mha; k_scoreg reads it before that).
    short* WeffT = (short*)(ws + 170921984);   //     262,144 B  (256,512)   bf16
    // beff overlays wsum (k_reduce writes wsum after k_scoreg reads beff).
    float* beff  = (float*)(ws + 170131456);   //       1,024 B  (256)       f32

    k_cvt<<<16384, 256, 0, stream>>>(x, x_bf);
    k_prep<<<320, 256, 0, stream>>>(alpha, alpha_out, zeros_out,
                                    wkv_w, wkv_b, wtq, WeffT, beff, wkvT);
    // v = (x @ wkv_w + b)[:, 512:]   (bf16 out, v-half only; k never hits HBM)
    mfma_gemm<true><<<dim3(4, 512), 256, 0, stream>>>(
        x_bf, wkvT + 512 * 512, wkv_b + 512, (void*)v, 512, 512, 0, 1 << 30, 2);
    // scores + softmax + sw_out + swT + pws, from x_bf directly via Weff
    k_scoreg<<<dim3(2, 512), 256, 0, stream>>>(
        x_bf, WeffT, beff, alpha, sw_out, swT, pws);
    k_wsum<<<2048, 256, 0, stream>>>(v, swT, pnum);
    k_reduce<<<260, 256, 0, stream>>>(pnum, pws, num, wsum);
    k_qkv<<<dim3(24, 4), 256, 0, stream>>>(num, wsum, qkv_w, qkvb);
    k_mha<<<32, 256, 0, stream>>>(qkvb, attn_out, ot);
    k_p<<<dim3(4, 32), 256, 0, stream>>>(ot, out_w, Pt);
    // out = swT @ Pt^T + out_b   (f32 out)
    mfma_gemm<false><<<dim3(4, 512), 256, 0, stream>>>(
        swT, Pt, out_b, (void*)out, 256, 512, 131072, 16384, 2);
}